// Round 28
// baseline (49.230 us; speedup 1.0000x reference)
//
#include <hip/hip_runtime.h>
#include <hip/hip_bf16.h>
#include <math.h>

// DifferentiableRAM: out[b,c,n,m] = gamma[b] * sum_h Fy[b,n,h] * sum_w x[b,c,h,w] * Fx[b,m,w]
// G[bc][m][h] = (x[bc] @ Fx[b]^T)^T ; out[bc][n][m] = gamma * Fy[b] @ G[bc]^T
// R28: R21 + (a) UNALIGNED k-windows: stage ceil(width/64) chunks from an
//      8px-aligned base instead of 64-aligned tiles (avg k-steps 3.17 -> ~2.7);
//      gemm1 dead-h test padded +-72px so gemm2's shifted coverage never reads
//      unwritten G. (b) dead-m skip in gemm2 (G[m]=0 there; write zeros direct).
// ws: Fx_b 8MB | Fy_b 8MB | G 25.2MB => 41.2 MB

namespace {

typedef __attribute__((ext_vector_type(8))) short v8s;    // 8 bf16
typedef __attribute__((ext_vector_type(4))) short v4s;    // 4 bf16 (8B)
typedef __attribute__((ext_vector_type(4))) float f32x4;  // MFMA C/D frag

constexpr int Bn = 32;
constexpr int Cc = 3;
constexpr int HW = 512;
constexpr int Nn = 256;
constexpr float SMALLF = 1e-4f;

__device__ inline unsigned short f2bf(float f) {
    __hip_bfloat16 h = __float2bfloat16(f);
    union { __hip_bfloat16 h; unsigned short u; } c;
    c.h = h;
    return c.u;
}

// bijective XCD swizzle (grid % 8 == 0)
__device__ inline int xcd_swz(int bid, int nwg) {
    return (bid & 7) * (nwg >> 3) + (bid >> 3);
}

// Unaligned 64-wide k-chunking for a Trows-row Gaussian filter tile at r0:
// returns 8px-aligned base and chunk count covering [mu_lo-4.5s-2, mu_hi+4.5s+2].
__device__ inline bool window_px(float g, float delta, float sigma,
                                 int r0, int Trows, int& base, int& nst) {
    float lo = g + delta * ((float)r0 - 128.5f) - 4.5f * sigma - 2.0f;
    float hi = g + delta * ((float)(r0 + Trows - 1) - 128.5f) + 4.5f * sigma + 2.0f;
    if (hi < 0.0f || lo > 511.0f) return false;
    int lo_c = max(0, (int)floorf(lo));
    int hi_c = min(511, (int)ceilf(hi));
    base = lo_c & ~7;
    nst = (hi_c + 1 - base + 63) >> 6;
    if (base + nst * 64 > 512) base = 512 - nst * 64;   // clamp (nst<=8 => base>=0)
    return true;
}

// ---------------- Kernel 1: Gaussian filterbanks (bf16 out) ---------------
__global__ __launch_bounds__(256) void fb_kernel(const float* __restrict__ p,
                                                 unsigned short* __restrict__ Fx,
                                                 unsigned short* __restrict__ Fy) {
    const int wid  = threadIdx.x >> 6;
    const int lane = threadIdx.x & 63;
    const int rid  = blockIdx.x * 4 + wid;        // 0..16383
    const int which = rid >> 13;
    const int r = rid & 8191;
    const int b = r >> 8;
    const int n = r & 255;

    const float* pb = p + b * 5;
    const float sigma2 = expf(pb[2]);
    const float delta  = expf(pb[3]) * (511.0f / 255.0f);
    const float g = (which == 0) ? (HW * (pb[0] + 1.0f) * 0.5f)
                                 : (HW * (pb[1] + 1.0f) * 0.5f);
    const float mu = g + delta * ((float)n - 128.5f);
    const float inv2s = 0.5f / sigma2;

    float f[8];
    float sum = 0.0f;
#pragma unroll
    for (int q = 0; q < 8; ++q) {
        float a = (float)(q * 64 + lane);
        float d = a - mu;
        f[q] = expf(-d * d * inv2s);
        sum += f[q];
    }
#pragma unroll
    for (int s = 1; s < 64; s <<= 1) sum += __shfl_xor(sum, s, 64);
    const float inv = 1.0f / (sum + SMALLF);

    unsigned short* dst = ((which == 0) ? Fx : Fy) + ((size_t)(b * Nn + n)) * HW;
#pragma unroll
    for (int q = 0; q < 8; ++q) dst[q * 64 + lane] = f2bf(f[q] * inv);
}

// ---------------- LDS helpers (XOR-swizzled, 64-col rows = 128B) -----------
__device__ inline v8s frag_read(const unsigned short* __restrict__ lds, int row, int kk, int lk) {
    int byte = row * 128 + (((kk * 64) + lk * 16) ^ ((row & 7) << 4));
    return *(const v8s*)((const char*)lds + byte);
}

// ---------------- Kernel 2: G[bc][m][h] = (x[bc] @ Fx_b[b]^T)^T ------------
// 64h x 64m tile; unaligned k chunks over the m-tile's window; dead-h skip.
// grid = 3072 (1D, XCD-swizzled): wg -> bc*32 + htile*4 + mtile
__global__ __launch_bounds__(256) void gemm1_kernel(const float* __restrict__ x,
                                                    const unsigned short* __restrict__ Fx_b,
                                                    const float* __restrict__ p,
                                                    unsigned short* __restrict__ G) {
    __shared__ unsigned short lds_all[2 * 64 * 64];
    unsigned short* As = lds_all;
    unsigned short* Bs = lds_all + 64 * 64;
    const int t = threadIdx.x;
    const int wg = xcd_swz(blockIdx.x, 3072);
    const int bc = wg >> 5, b = bc / 3;
    const int rem = wg & 31;
    const int h0 = (rem >> 2) * 64;
    const int m0 = (rem & 3) * 64;

    const float* pb = p + b * 5;
    const float sigma = sqrtf(expf(pb[2]));
    const float delta = expf(pb[3]) * (511.0f / 255.0f);

    // dead-h elimination (px, padded +-72 to cover gemm2's chunk over/undershoot)
    {
        const float gy = HW * (pb[1] + 1.0f) * 0.5f;
        float ulo = gy + delta * (0.0f - 128.5f) - 4.5f * sigma - 2.0f - 72.0f;
        float uhi = gy + delta * (255.0f - 128.5f) + 4.5f * sigma + 2.0f + 72.0f;
        if ((float)(h0 + 63) < ulo || (float)h0 > uhi) return;
    }

    const float* Ag = x + (size_t)bc * HW * HW + (size_t)h0 * HW;
    const unsigned short* Bg = Fx_b + (size_t)b * Nn * HW + (size_t)m0 * HW;

    const float gx = HW * (pb[0] + 1.0f) * 0.5f;
    int kbase = 0, nst = 0;
    bool live = window_px(gx, delta, sigma, m0, 64, kbase, nst);

    const int wid = t >> 6, lane = t & 63, lr = lane & 15, lk = lane >> 4;
    const int wr = (wid >> 1) * 32;   // h-offset within 64
    const int wc = (wid & 1) * 32;    // m-offset within 64

    const int srow = t >> 2;          // 0..63 staging row
    const int scq  = (t & 3) * 16;    // col quadrant (16 elems)

    f32x4 acc[2][2];
#pragma unroll
    for (int i = 0; i < 2; ++i)
#pragma unroll
        for (int j = 0; j < 2; ++j) acc[i][j] = (f32x4){0.f, 0.f, 0.f, 0.f};

    float4 xa[4];   // 16 floats of A
    v8s    fxv[2];  // 16 bf16 of B

#define G1_LOAD(K0)                                                              \
    {                                                                            \
        const float* s_ = Ag + (size_t)srow * HW + (K0) + scq;                   \
        xa[0] = *(const float4*)s_;                                              \
        xa[1] = *(const float4*)(s_ + 4);                                        \
        xa[2] = *(const float4*)(s_ + 8);                                        \
        xa[3] = *(const float4*)(s_ + 12);                                       \
        const unsigned short* b_ = Bg + (size_t)srow * HW + (K0) + scq;          \
        fxv[0] = *(const v8s*)b_;                                                \
        fxv[1] = *(const v8s*)(b_ + 8);                                          \
    }

    if (live) {
        G1_LOAD(kbase);
#pragma unroll 1
        for (int s = 0; s < nst; ++s) {
            __syncthreads();
            {   // convert + write staged regs to LDS (swizzled)
                unsigned short q[16];
#pragma unroll
                for (int i = 0; i < 4; ++i) {
                    q[i * 4 + 0] = f2bf(xa[i].x);
                    q[i * 4 + 1] = f2bf(xa[i].y);
                    q[i * 4 + 2] = f2bf(xa[i].z);
                    q[i * 4 + 3] = f2bf(xa[i].w);
                }
                int base = srow * 128;
                int sw = (srow & 7) << 4;
                *(v8s*)((char*)As + base + ((scq * 2) ^ sw))      = *(const v8s*)q;
                *(v8s*)((char*)As + base + ((scq * 2 + 16) ^ sw)) = *(const v8s*)(q + 8);
                *(v8s*)((char*)Bs + base + ((scq * 2) ^ sw))      = fxv[0];
                *(v8s*)((char*)Bs + base + ((scq * 2 + 16) ^ sw)) = fxv[1];
            }
            __syncthreads();
            if (s + 1 < nst) G1_LOAD(kbase + (s + 1) * 64);
#pragma unroll
            for (int kk = 0; kk < 2; ++kk) {
                v8s af[2], bf[2];
#pragma unroll
                for (int mi = 0; mi < 2; ++mi) af[mi] = frag_read(As, wr + mi * 16 + lr, kk, lk);
#pragma unroll
                for (int ni = 0; ni < 2; ++ni) bf[ni] = frag_read(Bs, wc + ni * 16 + lr, kk, lk);
#pragma unroll
                for (int mi = 0; mi < 2; ++mi)
#pragma unroll
                    for (int ni = 0; ni < 2; ++ni)
                        acc[mi][ni] = __builtin_amdgcn_mfma_f32_16x16x32_bf16(af[mi], bf[ni], acc[mi][ni], 0, 0, 0);
            }
        }
    }
#undef G1_LOAD

    // ---- Epilogue: LDS transpose -> coalesced G[m][h] stores --------------
    __syncthreads();
    {
        unsigned short* Ls = lds_all;   // [64][72]
#pragma unroll
        for (int mi = 0; mi < 2; ++mi)
#pragma unroll
            for (int ni = 0; ni < 2; ++ni) {
                int ml = wc + ni * 16 + lr;
                int hl = wr + mi * 16 + lk * 4;
                unsigned short q[4] = {f2bf(acc[mi][ni][0]), f2bf(acc[mi][ni][1]),
                                       f2bf(acc[mi][ni][2]), f2bf(acc[mi][ni][3])};
                *(v4s*)(Ls + ml * 72 + hl) = *(const v4s*)q;
            }
        __syncthreads();
        int ml = t >> 2;
        int hc = (t & 3) * 16;
        v8s v0 = *(const v8s*)(Ls + ml * 72 + hc);
        v8s v1 = *(const v8s*)(Ls + ml * 72 + hc + 8);
        unsigned short* dst = G + (size_t)bc * Nn * HW + (size_t)(m0 + ml) * HW + h0 + hc;
        *(v8s*)dst = v0;
        *(v8s*)(dst + 8) = v1;
    }
}

// ---------------- Kernel 3: out[bc][n][m] = gamma * Fy_b[b] @ G[bc]^T ------
// 64n x 64m tile; unaligned k chunks over the n-tile's Fy window; dead-m skip.
// grid = 1536 (1D, XCD-swizzled): wg -> bc*16 + ntile*4 + mtile
__global__ __launch_bounds__(256) void gemm2_kernel(const unsigned short* __restrict__ Fy_b,
                                                    const unsigned short* __restrict__ G,
                                                    const float* __restrict__ p,
                                                    float* __restrict__ out) {
    __shared__ unsigned short As[64 * 64];
    __shared__ unsigned short Bs[64 * 64];
    const int t = threadIdx.x;
    const int wg = xcd_swz(blockIdx.x, 1536);
    const int bc = wg >> 4, b = bc / 3;
    const int rem = wg & 15;
    const int n0 = (rem >> 2) * 64;
    const int m0 = (rem & 3) * 64;

    const unsigned short* Ag = Fy_b + (size_t)b * Nn * HW + (size_t)n0 * HW;
    const unsigned short* Bg = G + (size_t)bc * Nn * HW + (size_t)m0 * HW;

    const float* pb = p + b * 5;
    const float gamma = expf(pb[4]);
    const float sigma = sqrtf(expf(pb[2]));
    const float delta = expf(pb[3]) * (511.0f / 255.0f);
    const float gy = HW * (pb[1] + 1.0f) * 0.5f;
    int kbase = 0, nst = 0;
    bool live = window_px(gy, delta, sigma, n0, 64, kbase, nst);
    // dead-m skip: if this m-tile's Fx window is empty, G[m-tile] == 0
    {
        const float gx = HW * (pb[0] + 1.0f) * 0.5f;
        int b2, n2;
        if (!window_px(gx, delta, sigma, m0, 64, b2, n2)) live = false;
    }

    const int wid = t >> 6, lane = t & 63, lr = lane & 15, lk = lane >> 4;
    const int wr = (wid >> 1) * 32, wc = (wid & 1) * 32;

    const int srow = t >> 2;
    const int scq  = (t & 3) * 16;

    f32x4 acc[2][2];
#pragma unroll
    for (int i = 0; i < 2; ++i)
#pragma unroll
        for (int j = 0; j < 2; ++j) acc[i][j] = (f32x4){0.f, 0.f, 0.f, 0.f};

    v8s va[2], vb[2];

#define G2_LOAD(K0)                                                              \
    {                                                                            \
        const unsigned short* a_ = Ag + (size_t)srow * HW + (K0) + scq;          \
        const unsigned short* b_ = Bg + (size_t)srow * HW + (K0) + scq;          \
        va[0] = *(const v8s*)a_;                                                 \
        va[1] = *(const v8s*)(a_ + 8);                                           \
        vb[0] = *(const v8s*)b_;                                                 \
        vb[1] = *(const v8s*)(b_ + 8);                                           \
    }

    if (live) {
        G2_LOAD(kbase);
#pragma unroll 1
        for (int s = 0; s < nst; ++s) {
            __syncthreads();
            {
                int base = srow * 128;
                int sw = (srow & 7) << 4;
                *(v8s*)((char*)As + base + ((scq * 2) ^ sw))      = va[0];
                *(v8s*)((char*)As + base + ((scq * 2 + 16) ^ sw)) = va[1];
                *(v8s*)((char*)Bs + base + ((scq * 2) ^ sw))      = vb[0];
                *(v8s*)((char*)Bs + base + ((scq * 2 + 16) ^ sw)) = vb[1];
            }
            __syncthreads();
            if (s + 1 < nst) G2_LOAD(kbase + (s + 1) * 64);
#pragma unroll
            for (int kk = 0; kk < 2; ++kk) {
                v8s af[2], bf[2];
#pragma unroll
                for (int mi = 0; mi < 2; ++mi) af[mi] = frag_read(As, wr + mi * 16 + lr, kk, lk);
#pragma unroll
                for (int ni = 0; ni < 2; ++ni) bf[ni] = frag_read(Bs, wc + ni * 16 + lr, kk, lk);
#pragma unroll
                for (int mi = 0; mi < 2; ++mi)
#pragma unroll
                    for (int ni = 0; ni < 2; ++ni)
                        acc[mi][ni] = __builtin_amdgcn_mfma_f32_16x16x32_bf16(af[mi], bf[ni], acc[mi][ni], 0, 0, 0);
            }
        }
    }
#undef G2_LOAD

    float* Cg = out + (size_t)bc * Nn * Nn + (size_t)n0 * Nn + m0;
#pragma unroll
    for (int mi = 0; mi < 2; ++mi)
#pragma unroll
        for (int r = 0; r < 4; ++r) {
            int row = wr + mi * 16 + lk * 4 + r;
#pragma unroll
            for (int ni = 0; ni < 2; ++ni)
                Cg[(size_t)row * Nn + wc + ni * 16 + lr] = gamma * acc[mi][ni][r];
        }
}

} // anonymous namespace

extern "C" void kernel_launch(void* const* d_in, const int* in_sizes, int n_in,
                              void* d_out, int out_size, void* d_ws, size_t ws_size,
                              hipStream_t stream) {
    const float* x = (const float*)d_in[0];   // [32,3,512,512]
    const float* p = (const float*)d_in[1];   // [32,5]
    float* out = (float*)d_out;               // [32,3,256,256] f32

    char* ws = (char*)d_ws;
    unsigned short* Fx_b = (unsigned short*)ws;                    // 32*256*512
    unsigned short* Fy_b = Fx_b + (size_t)Bn * Nn * HW;            // 32*256*512
    unsigned short* G    = Fy_b + (size_t)Bn * Nn * HW;            // 96*256*512 ([bc][m][h])

    hipLaunchKernelGGL(fb_kernel, dim3(4096), dim3(256), 0, stream, p, Fx_b, Fy_b);
    hipLaunchKernelGGL(gemm1_kernel, dim3(3072), dim3(256), 0, stream, x, Fx_b, p, G);
    hipLaunchKernelGGL(gemm2_kernel, dim3(1536), dim3(256), 0, stream, Fy_b, G, p, out);
}

// Round 29
// 44.408 us; speedup vs baseline: 1.1086x; 1.1086x over previous
//
#include <hip/hip_runtime.h>
#include <hip/hip_bf16.h>
#include <math.h>

// DifferentiableRAM: out[b,c,n,m] = gamma[b] * sum_h Fy[b,n,h] * sum_w x[b,c,h,w] * Fx[b,m,w]
// G[bc][m][h] = (x[bc] @ Fx[b]^T)^T ; out[bc][n][m] = gamma * Fy[b] @ G[bc]^T
// R29 = R21 verbatim (best measured: 44.66us). Banded 64-aligned k-windows
//      (4.5 sigma margin), dead-h elimination, 64x64 tiles BK=64, XCD swizzle.
//      Ten structural variants all regressed/neutral vs this configuration.
// ws: Fx_b 8MB | Fy_b 8MB | G 25.2MB => 41.2 MB

namespace {

typedef __attribute__((ext_vector_type(8))) short v8s;    // 8 bf16
typedef __attribute__((ext_vector_type(4))) short v4s;    // 4 bf16 (8B)
typedef __attribute__((ext_vector_type(4))) float f32x4;  // MFMA C/D frag

constexpr int Bn = 32;
constexpr int Cc = 3;
constexpr int HW = 512;
constexpr int Nn = 256;
constexpr float SMALLF = 1e-4f;

__device__ inline unsigned short f2bf(float f) {
    __hip_bfloat16 h = __float2bfloat16(f);
    union { __hip_bfloat16 h; unsigned short u; } c;
    c.h = h;
    return c.u;
}

// bijective XCD swizzle (grid % 8 == 0)
__device__ inline int xcd_swz(int bid, int nwg) {
    return (bid & 7) * (nwg >> 3) + (bid >> 3);
}

// k-tile window [klo..khi] (64-wide tiles) for a Trows-row Gaussian filter
// tile starting at row r0; margin 4.5*sigma + 2 px. Returns false if empty.
__device__ inline bool tile_window_g(float g, float delta, float sigma,
                                     int r0, int Trows, int& klo, int& khi) {
    float lo = g + delta * ((float)r0 - 128.5f) - 4.5f * sigma - 2.0f;
    float hi = g + delta * ((float)(r0 + Trows - 1) - 128.5f) + 4.5f * sigma + 2.0f;
    if (hi < 0.0f || lo > 511.0f) return false;
    klo = max(0, (int)floorf(lo * (1.0f / 64.0f)));
    khi = min(7, (int)floorf(hi * (1.0f / 64.0f)));
    return khi >= klo;
}

// ---------------- Kernel 1: Gaussian filterbanks (bf16 out) ---------------
__global__ __launch_bounds__(256) void fb_kernel(const float* __restrict__ p,
                                                 unsigned short* __restrict__ Fx,
                                                 unsigned short* __restrict__ Fy) {
    const int wid  = threadIdx.x >> 6;
    const int lane = threadIdx.x & 63;
    const int rid  = blockIdx.x * 4 + wid;        // 0..16383
    const int which = rid >> 13;
    const int r = rid & 8191;
    const int b = r >> 8;
    const int n = r & 255;

    const float* pb = p + b * 5;
    const float sigma2 = expf(pb[2]);
    const float delta  = expf(pb[3]) * (511.0f / 255.0f);
    const float g = (which == 0) ? (HW * (pb[0] + 1.0f) * 0.5f)
                                 : (HW * (pb[1] + 1.0f) * 0.5f);
    const float mu = g + delta * ((float)n - 128.5f);
    const float inv2s = 0.5f / sigma2;

    float f[8];
    float sum = 0.0f;
#pragma unroll
    for (int q = 0; q < 8; ++q) {
        float a = (float)(q * 64 + lane);
        float d = a - mu;
        f[q] = expf(-d * d * inv2s);
        sum += f[q];
    }
#pragma unroll
    for (int s = 1; s < 64; s <<= 1) sum += __shfl_xor(sum, s, 64);
    const float inv = 1.0f / (sum + SMALLF);

    unsigned short* dst = ((which == 0) ? Fx : Fy) + ((size_t)(b * Nn + n)) * HW;
#pragma unroll
    for (int q = 0; q < 8; ++q) dst[q * 64 + lane] = f2bf(f[q] * inv);
}

// ---------------- LDS helpers (XOR-swizzled, 64-col rows = 128B) -----------
__device__ inline v8s frag_read(const unsigned short* __restrict__ lds, int row, int kk, int lk) {
    int byte = row * 128 + (((kk * 64) + lk * 16) ^ ((row & 7) << 4));
    return *(const v8s*)((const char*)lds + byte);
}

// ---------------- Kernel 2: G[bc][m][h] = (x[bc] @ Fx_b[b]^T)^T ------------
// 64h x 64m tile; k = w restricted to the m-tile's Gaussian window; whole
// block skipped if its h-tile is outside the union Fy window (never read).
// grid = 3072 (1D, XCD-swizzled): wg -> bc*32 + htile*4 + mtile
__global__ __launch_bounds__(256) void gemm1_kernel(const float* __restrict__ x,
                                                    const unsigned short* __restrict__ Fx_b,
                                                    const float* __restrict__ p,
                                                    unsigned short* __restrict__ G) {
    __shared__ unsigned short lds_all[2 * 64 * 64];
    unsigned short* As = lds_all;
    unsigned short* Bs = lds_all + 64 * 64;
    const int t = threadIdx.x;
    const int wg = xcd_swz(blockIdx.x, 3072);
    const int bc = wg >> 5, b = bc / 3;
    const int rem = wg & 31;
    const int h0 = (rem >> 2) * 64;
    const int m0 = (rem & 3) * 64;

    const float* pb = p + b * 5;
    const float sigma = sqrtf(expf(pb[2]));
    const float delta = expf(pb[3]) * (511.0f / 255.0f);

    // dead-h elimination: skip if this h-tile is never read by gemm2
    {
        const float gy = HW * (pb[1] + 1.0f) * 0.5f;
        int ulo, uhi;
        if (!tile_window_g(gy, delta, sigma, 0, 256, ulo, uhi)) return;
        int ht = h0 >> 6;
        if (ht < ulo || ht > uhi) return;
    }

    const float* Ag = x + (size_t)bc * HW * HW + (size_t)h0 * HW;
    const unsigned short* Bg = Fx_b + (size_t)b * Nn * HW + (size_t)m0 * HW;

    const float gx = HW * (pb[0] + 1.0f) * 0.5f;
    int klo = 0, khi = -1;
    bool live = tile_window_g(gx, delta, sigma, m0, 64, klo, khi);

    const int wid = t >> 6, lane = t & 63, lr = lane & 15, lk = lane >> 4;
    const int wr = (wid >> 1) * 32;   // h-offset within 64
    const int wc = (wid & 1) * 32;    // m-offset within 64

    const int srow = t >> 2;          // 0..63 staging row
    const int scq  = (t & 3) * 16;    // col quadrant (16 elems)

    f32x4 acc[2][2];
#pragma unroll
    for (int i = 0; i < 2; ++i)
#pragma unroll
        for (int j = 0; j < 2; ++j) acc[i][j] = (f32x4){0.f, 0.f, 0.f, 0.f};

    float4 xa[4];   // 16 floats of A
    v8s    fxv[2];  // 16 bf16 of B

#define G1_LOAD(K0)                                                              \
    {                                                                            \
        const float* s_ = Ag + (size_t)srow * HW + (K0) + scq;                   \
        xa[0] = *(const float4*)s_;                                              \
        xa[1] = *(const float4*)(s_ + 4);                                        \
        xa[2] = *(const float4*)(s_ + 8);                                        \
        xa[3] = *(const float4*)(s_ + 12);                                       \
        const unsigned short* b_ = Bg + (size_t)srow * HW + (K0) + scq;          \
        fxv[0] = *(const v8s*)b_;                                                \
        fxv[1] = *(const v8s*)(b_ + 8);                                          \
    }

    if (live) {
        G1_LOAD(klo * 64);
#pragma unroll 1
        for (int ks = klo; ks <= khi; ++ks) {
            __syncthreads();
            {   // convert + write staged regs to LDS (swizzled)
                unsigned short q[16];
#pragma unroll
                for (int i = 0; i < 4; ++i) {
                    q[i * 4 + 0] = f2bf(xa[i].x);
                    q[i * 4 + 1] = f2bf(xa[i].y);
                    q[i * 4 + 2] = f2bf(xa[i].z);
                    q[i * 4 + 3] = f2bf(xa[i].w);
                }
                int base = srow * 128;
                int sw = (srow & 7) << 4;
                *(v8s*)((char*)As + base + ((scq * 2) ^ sw))      = *(const v8s*)q;
                *(v8s*)((char*)As + base + ((scq * 2 + 16) ^ sw)) = *(const v8s*)(q + 8);
                *(v8s*)((char*)Bs + base + ((scq * 2) ^ sw))      = fxv[0];
                *(v8s*)((char*)Bs + base + ((scq * 2 + 16) ^ sw)) = fxv[1];
            }
            __syncthreads();
            if (ks < khi) G1_LOAD((ks + 1) * 64);
#pragma unroll
            for (int kk = 0; kk < 2; ++kk) {
                v8s af[2], bf[2];
#pragma unroll
                for (int mi = 0; mi < 2; ++mi) af[mi] = frag_read(As, wr + mi * 16 + lr, kk, lk);
#pragma unroll
                for (int ni = 0; ni < 2; ++ni) bf[ni] = frag_read(Bs, wc + ni * 16 + lr, kk, lk);
#pragma unroll
                for (int mi = 0; mi < 2; ++mi)
#pragma unroll
                    for (int ni = 0; ni < 2; ++ni)
                        acc[mi][ni] = __builtin_amdgcn_mfma_f32_16x16x32_bf16(af[mi], bf[ni], acc[mi][ni], 0, 0, 0);
            }
        }
    }
#undef G1_LOAD

    // ---- Epilogue: LDS transpose -> coalesced G[m][h] stores --------------
    __syncthreads();
    {
        unsigned short* Ls = lds_all;   // [64][72]
#pragma unroll
        for (int mi = 0; mi < 2; ++mi)
#pragma unroll
            for (int ni = 0; ni < 2; ++ni) {
                int ml = wc + ni * 16 + lr;
                int hl = wr + mi * 16 + lk * 4;
                unsigned short q[4] = {f2bf(acc[mi][ni][0]), f2bf(acc[mi][ni][1]),
                                       f2bf(acc[mi][ni][2]), f2bf(acc[mi][ni][3])};
                *(v4s*)(Ls + ml * 72 + hl) = *(const v4s*)q;
            }
        __syncthreads();
        int ml = t >> 2;
        int hc = (t & 3) * 16;
        v8s v0 = *(const v8s*)(Ls + ml * 72 + hc);
        v8s v1 = *(const v8s*)(Ls + ml * 72 + hc + 8);
        unsigned short* dst = G + (size_t)bc * Nn * HW + (size_t)(m0 + ml) * HW + h0 + hc;
        *(v8s*)dst = v0;
        *(v8s*)(dst + 8) = v1;
    }
}

// ---------------- Kernel 3: out[bc][n][m] = gamma * Fy_b[b] @ G[bc]^T ------
// 64n x 64m tile; k = h restricted to the n-tile's Gaussian window (Fy rows).
// grid = 1536 (1D, XCD-swizzled): wg -> bc*16 + ntile*4 + mtile
__global__ __launch_bounds__(256) void gemm2_kernel(const unsigned short* __restrict__ Fy_b,
                                                    const unsigned short* __restrict__ G,
                                                    const float* __restrict__ p,
                                                    float* __restrict__ out) {
    __shared__ unsigned short As[64 * 64];
    __shared__ unsigned short Bs[64 * 64];
    const int t = threadIdx.x;
    const int wg = xcd_swz(blockIdx.x, 1536);
    const int bc = wg >> 4, b = bc / 3;
    const int rem = wg & 15;
    const int n0 = (rem >> 2) * 64;
    const int m0 = (rem & 3) * 64;

    const unsigned short* Ag = Fy_b + (size_t)b * Nn * HW + (size_t)n0 * HW;
    const unsigned short* Bg = G + (size_t)bc * Nn * HW + (size_t)m0 * HW;

    const float* pb = p + b * 5;
    const float gamma = expf(pb[4]);
    const float sigma = sqrtf(expf(pb[2]));
    const float delta = expf(pb[3]) * (511.0f / 255.0f);
    const float gy = HW * (pb[1] + 1.0f) * 0.5f;
    int klo = 0, khi = -1;
    bool live = tile_window_g(gy, delta, sigma, n0, 64, klo, khi);

    const int wid = t >> 6, lane = t & 63, lr = lane & 15, lk = lane >> 4;
    const int wr = (wid >> 1) * 32, wc = (wid & 1) * 32;

    const int srow = t >> 2;
    const int scq  = (t & 3) * 16;

    f32x4 acc[2][2];
#pragma unroll
    for (int i = 0; i < 2; ++i)
#pragma unroll
        for (int j = 0; j < 2; ++j) acc[i][j] = (f32x4){0.f, 0.f, 0.f, 0.f};

    v8s va[2], vb[2];

#define G2_LOAD(K0)                                                              \
    {                                                                            \
        const unsigned short* a_ = Ag + (size_t)srow * HW + (K0) + scq;          \
        const unsigned short* b_ = Bg + (size_t)srow * HW + (K0) + scq;          \
        va[0] = *(const v8s*)a_;                                                 \
        va[1] = *(const v8s*)(a_ + 8);                                           \
        vb[0] = *(const v8s*)b_;                                                 \
        vb[1] = *(const v8s*)(b_ + 8);                                           \
    }

    if (live) {
        G2_LOAD(klo * 64);
#pragma unroll 1
        for (int ks = klo; ks <= khi; ++ks) {
            __syncthreads();
            {
                int base = srow * 128;
                int sw = (srow & 7) << 4;
                *(v8s*)((char*)As + base + ((scq * 2) ^ sw))      = va[0];
                *(v8s*)((char*)As + base + ((scq * 2 + 16) ^ sw)) = va[1];
                *(v8s*)((char*)Bs + base + ((scq * 2) ^ sw))      = vb[0];
                *(v8s*)((char*)Bs + base + ((scq * 2 + 16) ^ sw)) = vb[1];
            }
            __syncthreads();
            if (ks < khi) G2_LOAD((ks + 1) * 64);
#pragma unroll
            for (int kk = 0; kk < 2; ++kk) {
                v8s af[2], bf[2];
#pragma unroll
                for (int mi = 0; mi < 2; ++mi) af[mi] = frag_read(As, wr + mi * 16 + lr, kk, lk);
#pragma unroll
                for (int ni = 0; ni < 2; ++ni) bf[ni] = frag_read(Bs, wc + ni * 16 + lr, kk, lk);
#pragma unroll
                for (int mi = 0; mi < 2; ++mi)
#pragma unroll
                    for (int ni = 0; ni < 2; ++ni)
                        acc[mi][ni] = __builtin_amdgcn_mfma_f32_16x16x32_bf16(af[mi], bf[ni], acc[mi][ni], 0, 0, 0);
            }
        }
    }
#undef G2_LOAD

    float* Cg = out + (size_t)bc * Nn * Nn + (size_t)n0 * Nn + m0;
#pragma unroll
    for (int mi = 0; mi < 2; ++mi)
#pragma unroll
        for (int r = 0; r < 4; ++r) {
            int row = wr + mi * 16 + lk * 4 + r;
#pragma unroll
            for (int ni = 0; ni < 2; ++ni)
                Cg[(size_t)row * Nn + wc + ni * 16 + lr] = gamma * acc[mi][ni][r];
        }
}

} // anonymous namespace

extern "C" void kernel_launch(void* const* d_in, const int* in_sizes, int n_in,
                              void* d_out, int out_size, void* d_ws, size_t ws_size,
                              hipStream_t stream) {
    const float* x = (const float*)d_in[0];   // [32,3,512,512]
    const float* p = (const float*)d_in[1];   // [32,5]
    float* out = (float*)d_out;               // [32,3,256,256] f32

    char* ws = (char*)d_ws;
    unsigned short* Fx_b = (unsigned short*)ws;                    // 32*256*512
    unsigned short* Fy_b = Fx_b + (size_t)Bn * Nn * HW;            // 32*256*512
    unsigned short* G    = Fy_b + (size_t)Bn * Nn * HW;            // 96*256*512 ([bc][m][h])

    hipLaunchKernelGGL(fb_kernel, dim3(4096), dim3(256), 0, stream, p, Fx_b, Fy_b);
    hipLaunchKernelGGL(gemm1_kernel, dim3(3072), dim3(256), 0, stream, x, Fx_b, p, G);
    hipLaunchKernelGGL(gemm2_kernel, dim3(1536), dim3(256), 0, stream, Fy_b, G, p, out);
}